// Round 20
// baseline (79.593 us; speedup 1.0000x reference)
//
#include <hip/hip_runtime.h>

// NestedConv via MFMA bf16: B=64, N=128, D=64.
// out[b,i,j,:] = m[b,i,j] * sum_k A[b,k,j] * h[b,i,k,:]
// h = relu(relu((m*X)@W1+b1)@W2+b2),  A symmetric 0/1 (bf16-exact).
//
// Round-20 = Round-19 champion (78.8us) + ONE change: L1 operand-swapped
// (same fragment bytes; C transposes -> lane holds 4 consecutive d at fixed
// r) -> 8x uint2 H1 writes instead of 32x scalar ds_write_u16. Wave-banding
// preserved (no new barriers). R15/16 bundled this with the fragmented-NT
// store (the real regression, proven R18/R19); this isolates it.
#define Bv 64
#define Nv 128
#define Dv 64

// ws layout (bytes): [0,16K) wpk; [20480] flag; [32K, 32K+2M) apk.
#define FLAG_OFF_B 20480
#define APK_OFF_B  32768
#define WS_NEED (32768 + Bv * 32768)

typedef __attribute__((ext_vector_type(8))) short bf16x8;
typedef __attribute__((ext_vector_type(4))) float f32x4;

// f32 -> bf16 RNE, pure bit ops (schedulable)
__device__ __forceinline__ unsigned short f2bf(float f) {
    unsigned u = __float_as_uint(f);
    u += 0x7FFFu + ((u >> 16) & 1u);
    return (unsigned short)(u >> 16);
}
__device__ __forceinline__ unsigned pk2(float a, float b) {
    return (unsigned)f2bf(a) | ((unsigned)f2bf(b) << 16);
}
// relu + pack 4 accumulator floats -> 8B
__device__ __forceinline__ uint2 relu_pk4(f32x4 v) {
    return make_uint2(pk2(fmaxf(v[0], 0.f), fmaxf(v[1], 0.f)),
                      pk2(fmaxf(v[2], 0.f), fmaxf(v[3], 0.f)));
}

// XOR-swizzled byte address in a row-major LDS tile with 128 B rows
__device__ __forceinline__ int swz128(int r, int bi) {
    return r * 128 + (((bi & ~15) ^ ((r & 7) << 4)) | (bi & 15));
}

__device__ __forceinline__ bf16x8 pack8(float4 a, float4 b) {
    bf16x8 r;
    r[0] = (short)f2bf(a.x); r[1] = (short)f2bf(a.y);
    r[2] = (short)f2bf(a.z); r[3] = (short)f2bf(a.w);
    r[4] = (short)f2bf(b.x); r[5] = (short)f2bf(b.y);
    r[6] = (short)f2bf(b.z); r[7] = (short)f2bf(b.w);
    return r;
}

// fallback W fragment loader: 8 strided scalar loads (PRE=false only)
__device__ __forceinline__ bf16x8 load_w_frag(const float* __restrict__ W,
                                              int kkbase, int dn, int l15, int l16) {
    const float* p = W + (kkbase + 8 * l16) * Dv + dn + l15;
    bf16x8 r;
    #pragma unroll
    for (int t = 0; t < 8; ++t) r[t] = (short)f2bf(p[t * Dv]);
    return r;
}

// ---- merged pre-kernel: pack A (blocks 0-511), pack W (512-515), bias check (516) ----
__global__ void pack_all(const float* __restrict__ A,
                         const float* __restrict__ W1,
                         const float* __restrict__ W2,
                         const float* __restrict__ b1,
                         const float* __restrict__ b2,
                         unsigned short* __restrict__ wpk,
                         unsigned short* __restrict__ apk,
                         int* __restrict__ flag) {
    const int blk = blockIdx.x;
    const int tid = threadIdx.x;
    if (blk < 512) {
        // Apk[b][jt][kk][l][t] = A[b][jt*16+(l&15)][kk*32+8*(l>>4)+t]
        const int gid = blk * 256 + tid;                  // 131072 items
        const int l = gid & 63, f = gid >> 6;             // f = b*32 + jt*4 + kk
        const int b = f >> 5, r = f & 31, jt = r >> 2, kk = r & 3;
        const float4* p = (const float4*)(A +
            ((size_t)(b * Nv + jt * 16 + (l & 15))) * Nv + kk * 32 + 8 * (l >> 4));
        *(bf16x8*)(apk + (size_t)f * 512 + l * 8) = pack8(p[0], p[1]);
    } else if (blk < 516) {
        // Wpk[f][l][t], f = layer*8 + kk*4 + tn; value = W[kk*32+8*(l>>4)+t][tn*16+(l&15)]
        const int idx = (blk - 512) * 256 + tid;          // 1024 items
        const int l = idx & 63, f = idx >> 6;
        const int layer = f >> 3, kk = (f >> 2) & 1, tn = f & 3;
        const float* W = layer ? W2 : W1;
        const float* p = W + (kk * 32 + 8 * (l >> 4)) * Dv + tn * 16 + (l & 15);
        unsigned short* o = wpk + f * 512 + l * 8;
        #pragma unroll
        for (int t = 0; t < 8; ++t) o[t] = f2bf(p[t * Dv]);
    } else {
        // flag = 1 iff all biases exactly zero
        __shared__ int nz;
        if (tid == 0) nz = 0;
        __syncthreads();
        if (tid < 128) {
            const float v = (tid < 64) ? b1[tid] : b2[tid - 64];
            if (v != 0.0f) atomicOr(&nz, 1);
        }
        __syncthreads();
        if (tid == 0) flag[0] = (nz == 0) ? 1 : 0;
    }
}

template <bool PRE>
__global__ __launch_bounds__(256, 3)
void nested_conv_mfma(const float* __restrict__ X,
                      const float* __restrict__ A,
                      const int*   __restrict__ mask,
                      const float* __restrict__ W1,
                      const float* __restrict__ b1,
                      const float* __restrict__ W2,
                      const float* __restrict__ b2,
                      const unsigned short* __restrict__ wpk,
                      const unsigned short* __restrict__ apk,
                      const int*   __restrict__ bzflag,
                      float* __restrict__ out)
{
    // One 16 KB buffer: Xs[128][64] -> H1[128][64] -> H2T[64][128] (bf16) -> Sout[64][64] f32
    __shared__ __align__(16) unsigned char Sb[16384];

    const int i = blockIdx.x, b = blockIdx.y;
    const int tid = threadIdx.x;
    const int l   = tid & 63;
    const int w   = tid >> 6;       // wave 0..3
    const int l15 = l & 15;
    const int l16 = l >> 4;

    const size_t bi_base = (size_t)(b * Nv + i);
    const int flz = PRE ? bzflag[0] : 0;   // 1 => biases zero => masked rows' X dead

    // ---- stage masked X as bf16 into Xs[r][d] (swizzled; rows tid>>1 are
    //      wave-banded: wave w covers rows [32w, 32w+32)) ----
    {
        const int r    = tid >> 1;
        const int half = (tid & 1) << 5;     // d offset 0 or 32
        const float mm = mask[bi_base * Nv + r] ? 1.0f : 0.0f;
        const float4* xp = (const float4*)(X + (bi_base * Nv + r) * Dv + half);
        if (!flz || mm != 0.0f) {
            #pragma unroll
            for (int g = 0; g < 4; ++g) {
                const float4 v0 = xp[2 * g], v1 = xp[2 * g + 1];
                bf16x8 pk;
                pk[0] = (short)f2bf(mm * v0.x); pk[1] = (short)f2bf(mm * v0.y);
                pk[2] = (short)f2bf(mm * v0.z); pk[3] = (short)f2bf(mm * v0.w);
                pk[4] = (short)f2bf(mm * v1.x); pk[5] = (short)f2bf(mm * v1.y);
                pk[6] = (short)f2bf(mm * v1.z); pk[7] = (short)f2bf(mm * v1.w);
                *(bf16x8*)&Sb[swz128(r, 2 * half + 16 * g)] = pk;
            }
        } else {
            const bf16x8 z = {0, 0, 0, 0, 0, 0, 0, 0};
            #pragma unroll
            for (int g = 0; g < 4; ++g)
                *(bf16x8*)&Sb[swz128(r, 2 * half + 16 * g)] = z;
        }
    }
    // no barrier: L1 reads only this wave's row band (same-wave lgkm ordering)

    // ===== L1 (SWAPPED): H1T-tile = mfma(W1T-frag, XmT-frag) =====
    // xf = same LDS fragment bytes as non-swapped A-operand (layouts coincide);
    // C transposes: lane holds 4 consecutive d at fixed r -> uint2 H1 writes.
    bf16x8 xf[2][2];   // [rr][kk]
    #pragma unroll
    for (int rr = 0; rr < 2; ++rr)
        #pragma unroll
        for (int kk = 0; kk < 2; ++kk) {
            const int r = (2 * w + rr) * 16 + l15;
            xf[rr][kk] = *(const bf16x8*)&Sb[r * 128 + ((kk * 64 + 16 * l16) ^ ((r & 7) << 4))];
        }
    f32x4 acc1[2][4];
    #pragma unroll
    for (int dt = 0; dt < 4; ++dt) {   // C rows = d: init b1[dt*16 + 4*l16 + e]
        const float4 bv = *(const float4*)&b1[dt * 16 + 4 * l16];
        acc1[0][dt] = (f32x4){bv.x, bv.y, bv.z, bv.w};
        acc1[1][dt] = acc1[0][dt];
    }
    #pragma unroll
    for (int kk = 0; kk < 2; ++kk)
        #pragma unroll
        for (int dt = 0; dt < 4; ++dt) {
            const bf16x8 wf = PRE
                ? *(const bf16x8*)(wpk + (0 * 8 + kk * 4 + dt) * 512 + l * 8)
                : load_w_frag(W1, kk * 32, dt * 16, l15, l16);
            acc1[0][dt] = __builtin_amdgcn_mfma_f32_16x16x32_bf16(wf, xf[0][kk], acc1[0][dt], 0, 0, 0);
            acc1[1][dt] = __builtin_amdgcn_mfma_f32_16x16x32_bf16(wf, xf[1][kk], acc1[1][dt], 0, 0, 0);
        }
    // H1[r][d] vector writes: r = (2w+rr)*16+l15 (own band), d-block = dt*32+8*l16
    #pragma unroll
    for (int rr = 0; rr < 2; ++rr) {
        const int r = (2 * w + rr) * 16 + l15;
        #pragma unroll
        for (int dt = 0; dt < 4; ++dt)
            *(uint2*)&Sb[swz128(r, dt * 32 + l16 * 8)] = relu_pk4(acc1[rr][dt]);
    }
    // no barrier: L2 reads only this wave's own H1 band

    f32x4 acc[2][4];

    // ================= layer 2 (normal): H2 = relu(H1 @ W2 + b2) =================
    #pragma unroll
    for (int tn = 0; tn < 4; ++tn) {
        const float bv = b2[tn * 16 + l15];
        acc[0][tn] = (f32x4){bv, bv, bv, bv};
        acc[1][tn] = acc[0][tn];
    }
    #pragma unroll
    for (int kk = 0; kk < 2; ++kk) {
        bf16x8 af[2];
        #pragma unroll
        for (int mm = 0; mm < 2; ++mm) {
            const int r = (2 * w + mm) * 16 + l15;
            af[mm] = *(const bf16x8*)&Sb[r * 128 + ((kk * 64 + 16 * l16) ^ ((l15 & 7) << 4))];
        }
        #pragma unroll
        for (int tn = 0; tn < 4; ++tn) {
            const bf16x8 wf = PRE
                ? *(const bf16x8*)(wpk + (1 * 8 + kk * 4 + tn) * 512 + l * 8)
                : load_w_frag(W2, kk * 32, tn * 16, l15, l16);
            acc[0][tn] = __builtin_amdgcn_mfma_f32_16x16x32_bf16(af[0], wf, acc[0][tn], 0, 0, 0);
            acc[1][tn] = __builtin_amdgcn_mfma_f32_16x16x32_bf16(af[1], wf, acc[1][tn], 0, 0, 0);
        }
    }
    __syncthreads();   // barrier #1 (REQUIRED): all waves' H1 reads done —
                       // H2T writes below touch every wave's band

    // write H2T[d][k] (lane's 4 C-regs are 4 consecutive k at fixed d -> one 8 B write)
    #pragma unroll
    for (int mm = 0; mm < 2; ++mm)
        #pragma unroll
        for (int tn = 0; tn < 4; ++tn) {
            const int d  = tn * 16 + l15;
            const int kb = (2 * w + mm) * 16 + 4 * l16;
            const int inrow = 2 * kb;   // multiple of 8
            const int addr  = d * 256 + (((inrow & ~15) ^ ((d & 7) << 4)) | (inrow & 15));
            *(uint2*)&Sb[addr] = relu_pk4(acc[mm][tn]);
        }
    __syncthreads();   // barrier #2 (REQUIRED): H2T published, read cross-wave

    // ======= phase 2 (SWAPPED): outT[d][j] = mfma(H2T-frag, Apk-frag) =======
    f32x4 accO[2][4];
    #pragma unroll
    for (int jj = 0; jj < 2; ++jj)
        #pragma unroll
        for (int dt = 0; dt < 4; ++dt)
            accO[jj][dt] = (f32x4){0.f, 0.f, 0.f, 0.f};

    const float* Ab = A + (size_t)b * Nv * Nv;
    const unsigned short* Apb = apk + (size_t)b * 32 * 512;
    #pragma unroll
    for (int kk = 0; kk < 4; ++kk) {
        bf16x8 anf[2];
        #pragma unroll
        for (int jj = 0; jj < 2; ++jj) {
            const int jt = 2 * w + jj;
            if (PRE) {
                anf[jj] = *(const bf16x8*)(Apb + (jt * 4 + kk) * 512 + l * 8);
            } else {
                const float4* ap = (const float4*)(Ab + (size_t)(jt * 16 + l15) * Nv + kk * 32 + 8 * l16);
                anf[jj] = pack8(ap[0], ap[1]);
            }
        }
        #pragma unroll
        for (int dt = 0; dt < 4; ++dt) {
            const int d = dt * 16 + l15;
            const bf16x8 hf = *(const bf16x8*)&Sb[d * 256 + ((kk * 64 + 16 * l16) ^ ((l15 & 7) << 4))];
            accO[0][dt] = __builtin_amdgcn_mfma_f32_16x16x32_bf16(hf, anf[0], accO[0][dt], 0, 0, 0);
            accO[1][dt] = __builtin_amdgcn_mfma_f32_16x16x32_bf16(hf, anf[1], accO[1][dt], 0, 0, 0);
        }
    }
    __syncthreads();   // barrier #3 (REQUIRED): all H2T reads done; Sb -> Sout

    // ---- store via LDS transpose: full-line NT stores (1KB contiguous/instr) ----
    const int* mrow = mask + bi_base * Nv;
    float* Ob = out + bi_base * Nv * Dv;
    #pragma unroll
    for (int jj = 0; jj < 2; ++jj) {
        const int jrow = (2 * w + jj) * 16 + l15;        // this lane's out row
        const float msk = mrow[jrow] ? 1.0f : 0.0f;
        const int lr = w * 16 + l15;                     // LDS row (own band)
        #pragma unroll
        for (int dt = 0; dt < 4; ++dt) {                 // d-block bi = 4*dt + l16
            const f32x4 v = accO[jj][dt];
            const f32x4 sv = {v[0] * msk, v[1] * msk, v[2] * msk, v[3] * msk};
            const int bip = (4 * dt + l16) ^ l15;
            *(f32x4*)&Sb[lr * 256 + bip * 16] = sv;
        }
        #pragma unroll
        for (int q = 0; q < 4; ++q) {                    // read 4 rows x 256B = 1KB
            const int lrr = w * 16 + 4 * q + l16;
            const int bir = l15 ^ (4 * q + l16);
            const f32x4 sv = *(const f32x4*)&Sb[lrr * 256 + bir * 16];
            const int j = (2 * w + jj) * 16 + 4 * q + l16;
            __builtin_nontemporal_store(sv, (f32x4*)(Ob + (size_t)j * Dv + 4 * l15));
        }
    }
}

extern "C" void kernel_launch(void* const* d_in, const int* in_sizes, int n_in,
                              void* d_out, int out_size, void* d_ws, size_t ws_size,
                              hipStream_t stream) {
    const float* X    = (const float*)d_in[0];
    const float* A    = (const float*)d_in[1];
    const int*   mask = (const int*)d_in[2];
    const float* W1   = (const float*)d_in[3];
    const float* b1   = (const float*)d_in[4];
    const float* W2   = (const float*)d_in[5];
    const float* b2   = (const float*)d_in[6];
    float* out = (float*)d_out;

    dim3 grid(Nv, Bv);   // (i, b): blocks sharing b are adjacent -> A[b] L2-hot

    if (ws_size >= (size_t)WS_NEED) {
        unsigned char* ws = (unsigned char*)d_ws;
        unsigned short* wpk  = (unsigned short*)ws;
        int*            flag = (int*)(ws + FLAG_OFF_B);
        unsigned short* apk  = (unsigned short*)(ws + APK_OFF_B);
        pack_all<<<517, 256, 0, stream>>>(A, W1, W2, b1, b2, wpk, apk, flag);
        nested_conv_mfma<true><<<grid, 256, 0, stream>>>(
            X, A, mask, W1, b1, W2, b2, wpk, apk, flag, out);
    } else {
        nested_conv_mfma<false><<<grid, 256, 0, stream>>>(
            X, A, mask, W1, b1, W2, b2, nullptr, nullptr, nullptr, out);
    }
}

// Round 21
// 78.819 us; speedup vs baseline: 1.0098x; 1.0098x over previous
//
#include <hip/hip_runtime.h>

// NestedConv via MFMA bf16: B=64, N=128, D=64.
// out[b,i,j,:] = m[b,i,j] * sum_k A[b,k,j] * h[b,i,k,:]
// h = relu(relu((m*X)@W1+b1)@W2+b2),  A symmetric 0/1 (bf16-exact).
//
// Round-21 = exact revert to Round-19 champion (78.8us). R20's L1-swap was a
// null (-0.8us); this restores the best measured configuration:
//  - staged coalesced X front-end + zero-row X-skip (bias==0 device flag)
//  - minimal barriers (3), merged single pre-kernel
//  - swapped P2 + LDS-transpose store: full-line (1KB/wave-instr) NT stores,
//    WRITE exactly compulsory 268 MB (no partial-line amplification)
#define Bv 64
#define Nv 128
#define Dv 64

// ws layout (bytes): [0,16K) wpk; [20480] flag; [32K, 32K+2M) apk.
#define FLAG_OFF_B 20480
#define APK_OFF_B  32768
#define WS_NEED (32768 + Bv * 32768)

typedef __attribute__((ext_vector_type(8))) short bf16x8;
typedef __attribute__((ext_vector_type(4))) float f32x4;

// f32 -> bf16 RNE, pure bit ops
__device__ __forceinline__ unsigned short f2bf(float f) {
    unsigned u = __float_as_uint(f);
    u += 0x7FFFu + ((u >> 16) & 1u);
    return (unsigned short)(u >> 16);
}

// XOR-swizzled byte address in a row-major LDS tile with 128 B rows
__device__ __forceinline__ int swz128(int r, int bi) {
    return r * 128 + (((bi & ~15) ^ ((r & 7) << 4)) | (bi & 15));
}

__device__ __forceinline__ bf16x8 pack8(float4 a, float4 b) {
    bf16x8 r;
    r[0] = (short)f2bf(a.x); r[1] = (short)f2bf(a.y);
    r[2] = (short)f2bf(a.z); r[3] = (short)f2bf(a.w);
    r[4] = (short)f2bf(b.x); r[5] = (short)f2bf(b.y);
    r[6] = (short)f2bf(b.z); r[7] = (short)f2bf(b.w);
    return r;
}

// fallback W fragment loader: 8 strided scalar loads (PRE=false only)
__device__ __forceinline__ bf16x8 load_w_frag(const float* __restrict__ W,
                                              int kkbase, int dn, int l15, int l16) {
    const float* p = W + (kkbase + 8 * l16) * Dv + dn + l15;
    bf16x8 r;
    #pragma unroll
    for (int t = 0; t < 8; ++t) r[t] = (short)f2bf(p[t * Dv]);
    return r;
}

// ---- merged pre-kernel: pack A (blocks 0-511), pack W (512-515), bias check (516) ----
__global__ void pack_all(const float* __restrict__ A,
                         const float* __restrict__ W1,
                         const float* __restrict__ W2,
                         const float* __restrict__ b1,
                         const float* __restrict__ b2,
                         unsigned short* __restrict__ wpk,
                         unsigned short* __restrict__ apk,
                         int* __restrict__ flag) {
    const int blk = blockIdx.x;
    const int tid = threadIdx.x;
    if (blk < 512) {
        // Apk[b][jt][kk][l][t] = A[b][jt*16+(l&15)][kk*32+8*(l>>4)+t]
        const int gid = blk * 256 + tid;                  // 131072 items
        const int l = gid & 63, f = gid >> 6;             // f = b*32 + jt*4 + kk
        const int b = f >> 5, r = f & 31, jt = r >> 2, kk = r & 3;
        const float4* p = (const float4*)(A +
            ((size_t)(b * Nv + jt * 16 + (l & 15))) * Nv + kk * 32 + 8 * (l >> 4));
        *(bf16x8*)(apk + (size_t)f * 512 + l * 8) = pack8(p[0], p[1]);
    } else if (blk < 516) {
        // Wpk[f][l][t], f = layer*8 + kk*4 + tn; value = W[kk*32+8*(l>>4)+t][tn*16+(l&15)]
        const int idx = (blk - 512) * 256 + tid;          // 1024 items
        const int l = idx & 63, f = idx >> 6;
        const int layer = f >> 3, kk = (f >> 2) & 1, tn = f & 3;
        const float* W = layer ? W2 : W1;
        const float* p = W + (kk * 32 + 8 * (l >> 4)) * Dv + tn * 16 + (l & 15);
        unsigned short* o = wpk + f * 512 + l * 8;
        #pragma unroll
        for (int t = 0; t < 8; ++t) o[t] = f2bf(p[t * Dv]);
    } else {
        // flag = 1 iff all biases exactly zero
        __shared__ int nz;
        if (tid == 0) nz = 0;
        __syncthreads();
        if (tid < 128) {
            const float v = (tid < 64) ? b1[tid] : b2[tid - 64];
            if (v != 0.0f) atomicOr(&nz, 1);
        }
        __syncthreads();
        if (tid == 0) flag[0] = (nz == 0) ? 1 : 0;
    }
}

template <bool PRE>
__global__ __launch_bounds__(256, 3)
void nested_conv_mfma(const float* __restrict__ X,
                      const float* __restrict__ A,
                      const int*   __restrict__ mask,
                      const float* __restrict__ W1,
                      const float* __restrict__ b1,
                      const float* __restrict__ W2,
                      const float* __restrict__ b2,
                      const unsigned short* __restrict__ wpk,
                      const unsigned short* __restrict__ apk,
                      const int*   __restrict__ bzflag,
                      float* __restrict__ out)
{
    // One 16 KB buffer: Xs[128][64] -> H1[128][64] -> H2T[64][128] (bf16) -> Sout[64][64] f32
    __shared__ __align__(16) unsigned char Sb[16384];

    const int i = blockIdx.x, b = blockIdx.y;
    const int tid = threadIdx.x;
    const int l   = tid & 63;
    const int w   = tid >> 6;       // wave 0..3
    const int l15 = l & 15;
    const int l16 = l >> 4;

    const size_t bi_base = (size_t)(b * Nv + i);
    const int flz = PRE ? bzflag[0] : 0;   // 1 => biases zero => masked rows' X dead

    // ---- stage masked X as bf16 into Xs[r][d] (swizzled; rows tid>>1 are
    //      wave-banded: wave w covers rows [32w, 32w+32)) ----
    {
        const int r    = tid >> 1;
        const int half = (tid & 1) << 5;     // d offset 0 or 32
        const float mm = mask[bi_base * Nv + r] ? 1.0f : 0.0f;
        const float4* xp = (const float4*)(X + (bi_base * Nv + r) * Dv + half);
        if (!flz || mm != 0.0f) {
            #pragma unroll
            for (int g = 0; g < 4; ++g) {
                const float4 v0 = xp[2 * g], v1 = xp[2 * g + 1];
                bf16x8 pk;
                pk[0] = (short)f2bf(mm * v0.x); pk[1] = (short)f2bf(mm * v0.y);
                pk[2] = (short)f2bf(mm * v0.z); pk[3] = (short)f2bf(mm * v0.w);
                pk[4] = (short)f2bf(mm * v1.x); pk[5] = (short)f2bf(mm * v1.y);
                pk[6] = (short)f2bf(mm * v1.z); pk[7] = (short)f2bf(mm * v1.w);
                *(bf16x8*)&Sb[swz128(r, 2 * half + 16 * g)] = pk;
            }
        } else {
            const bf16x8 z = {0, 0, 0, 0, 0, 0, 0, 0};
            #pragma unroll
            for (int g = 0; g < 4; ++g)
                *(bf16x8*)&Sb[swz128(r, 2 * half + 16 * g)] = z;
        }
    }
    // no barrier: L1 reads only this wave's row band (same-wave lgkm ordering)

    f32x4 acc[2][4];

    // ================= layer 1: H1 = relu(Xs @ W1 + b1) =================
    #pragma unroll
    for (int tn = 0; tn < 4; ++tn) {
        const float bv = b1[tn * 16 + l15];
        acc[0][tn] = (f32x4){bv, bv, bv, bv};
        acc[1][tn] = acc[0][tn];
    }
    #pragma unroll
    for (int kk = 0; kk < 2; ++kk) {
        bf16x8 af[2];
        #pragma unroll
        for (int mm = 0; mm < 2; ++mm) {
            const int r = (2 * w + mm) * 16 + l15;
            af[mm] = *(const bf16x8*)&Sb[r * 128 + ((kk * 64 + 16 * l16) ^ ((l15 & 7) << 4))];
        }
        #pragma unroll
        for (int tn = 0; tn < 4; ++tn) {
            const bf16x8 wf = PRE
                ? *(const bf16x8*)(wpk + (0 * 8 + kk * 4 + tn) * 512 + l * 8)
                : load_w_frag(W1, kk * 32, tn * 16, l15, l16);
            acc[0][tn] = __builtin_amdgcn_mfma_f32_16x16x32_bf16(af[0], wf, acc[0][tn], 0, 0, 0);
            acc[1][tn] = __builtin_amdgcn_mfma_f32_16x16x32_bf16(af[1], wf, acc[1][tn], 0, 0, 0);
        }
    }
    // no barrier: H1 writes land in this wave's own row band

    // write H1[r][d] (C-layout: row = tile*16 + 4*l16 + rg, col = tn*16 + l15)
    #pragma unroll
    for (int mm = 0; mm < 2; ++mm)
        #pragma unroll
        for (int tn = 0; tn < 4; ++tn)
            #pragma unroll
            for (int rg = 0; rg < 4; ++rg) {
                const int r = (2 * w + mm) * 16 + 4 * l16 + rg;
                const int d = tn * 16 + l15;
                *(unsigned short*)&Sb[swz128(r, 2 * d)] =
                    f2bf(fmaxf(acc[mm][tn][rg], 0.0f));
            }
    // no barrier: L2 reads only this wave's own H1 band

    // ================= layer 2: H2 = relu(H1 @ W2 + b2) =================
    #pragma unroll
    for (int tn = 0; tn < 4; ++tn) {
        const float bv = b2[tn * 16 + l15];
        acc[0][tn] = (f32x4){bv, bv, bv, bv};
        acc[1][tn] = acc[0][tn];
    }
    #pragma unroll
    for (int kk = 0; kk < 2; ++kk) {
        bf16x8 af[2];
        #pragma unroll
        for (int mm = 0; mm < 2; ++mm) {
            const int r = (2 * w + mm) * 16 + l15;
            af[mm] = *(const bf16x8*)&Sb[r * 128 + ((kk * 64 + 16 * l16) ^ ((l15 & 7) << 4))];
        }
        #pragma unroll
        for (int tn = 0; tn < 4; ++tn) {
            const bf16x8 wf = PRE
                ? *(const bf16x8*)(wpk + (1 * 8 + kk * 4 + tn) * 512 + l * 8)
                : load_w_frag(W2, kk * 32, tn * 16, l15, l16);
            acc[0][tn] = __builtin_amdgcn_mfma_f32_16x16x32_bf16(af[0], wf, acc[0][tn], 0, 0, 0);
            acc[1][tn] = __builtin_amdgcn_mfma_f32_16x16x32_bf16(af[1], wf, acc[1][tn], 0, 0, 0);
        }
    }
    __syncthreads();   // barrier #1 (REQUIRED): all waves' H1 reads done —
                       // H2T writes below touch every wave's band

    // write H2T[d][k] (lane's 4 C-regs are 4 consecutive k at fixed d -> one 8 B write)
    #pragma unroll
    for (int mm = 0; mm < 2; ++mm)
        #pragma unroll
        for (int tn = 0; tn < 4; ++tn) {
            const int d  = tn * 16 + l15;
            const int kb = (2 * w + mm) * 16 + 4 * l16;
            unsigned p0 = (unsigned)f2bf(fmaxf(acc[mm][tn][0], 0.0f))
                        | ((unsigned)f2bf(fmaxf(acc[mm][tn][1], 0.0f)) << 16);
            unsigned p1 = (unsigned)f2bf(fmaxf(acc[mm][tn][2], 0.0f))
                        | ((unsigned)f2bf(fmaxf(acc[mm][tn][3], 0.0f)) << 16);
            const int inrow = 2 * kb;   // multiple of 8
            const int addr  = d * 256 + (((inrow & ~15) ^ ((d & 7) << 4)) | (inrow & 15));
            *(uint2*)&Sb[addr] = make_uint2(p0, p1);
        }
    __syncthreads();   // barrier #2 (REQUIRED): H2T published, read cross-wave

    // ======= phase 2 (SWAPPED): outT[d][j] = mfma(H2T-frag, Apk-frag) =======
    // Same fragment bytes as the normal form; C transposes: lane holds 4
    // consecutive d (one 16B block) at fixed j.
    f32x4 accO[2][4];
    #pragma unroll
    for (int jj = 0; jj < 2; ++jj)
        #pragma unroll
        for (int dt = 0; dt < 4; ++dt)
            accO[jj][dt] = (f32x4){0.f, 0.f, 0.f, 0.f};

    const float* Ab = A + (size_t)b * Nv * Nv;
    const unsigned short* Apb = apk + (size_t)b * 32 * 512;
    #pragma unroll
    for (int kk = 0; kk < 4; ++kk) {
        bf16x8 anf[2];
        #pragma unroll
        for (int jj = 0; jj < 2; ++jj) {
            const int jt = 2 * w + jj;
            if (PRE) {
                anf[jj] = *(const bf16x8*)(Apb + (jt * 4 + kk) * 512 + l * 8);
            } else {
                const float4* ap = (const float4*)(Ab + (size_t)(jt * 16 + l15) * Nv + kk * 32 + 8 * l16);
                anf[jj] = pack8(ap[0], ap[1]);
            }
        }
        #pragma unroll
        for (int dt = 0; dt < 4; ++dt) {
            const int d = dt * 16 + l15;
            const bf16x8 hf = *(const bf16x8*)&Sb[d * 256 + ((kk * 64 + 16 * l16) ^ ((l15 & 7) << 4))];
            accO[0][dt] = __builtin_amdgcn_mfma_f32_16x16x32_bf16(hf, anf[0], accO[0][dt], 0, 0, 0);
            accO[1][dt] = __builtin_amdgcn_mfma_f32_16x16x32_bf16(hf, anf[1], accO[1][dt], 0, 0, 0);
        }
    }
    __syncthreads();   // barrier #3 (REQUIRED): all H2T reads done; Sb -> Sout

    // ---- store via LDS transpose: full-line NT stores (1KB contiguous/instr) ----
    // Sout half = 64 rows x 64 f32 = 16KB. Wave-private row band lr in
    // [16w, 16w+16) both for writes and reads -> no further barriers.
    // 16B-block swizzle bi' = bi ^ (lr&15): even bank spread both directions.
    const int* mrow = mask + bi_base * Nv;
    float* Ob = out + bi_base * Nv * Dv;
    #pragma unroll
    for (int jj = 0; jj < 2; ++jj) {
        const int jrow = (2 * w + jj) * 16 + l15;        // this lane's out row
        const float msk = mrow[jrow] ? 1.0f : 0.0f;
        const int lr = w * 16 + l15;                     // LDS row (own band)
        #pragma unroll
        for (int dt = 0; dt < 4; ++dt) {                 // d-block bi = 4*dt + l16
            const f32x4 v = accO[jj][dt];
            const f32x4 sv = {v[0] * msk, v[1] * msk, v[2] * msk, v[3] * msk};
            const int bip = (4 * dt + l16) ^ l15;
            *(f32x4*)&Sb[lr * 256 + bip * 16] = sv;
        }
        #pragma unroll
        for (int q = 0; q < 4; ++q) {                    // read 4 rows x 256B = 1KB
            const int lrr = w * 16 + 4 * q + l16;
            const int bir = l15 ^ (4 * q + l16);
            const f32x4 sv = *(const f32x4*)&Sb[lrr * 256 + bir * 16];
            const int j = (2 * w + jj) * 16 + 4 * q + l16;
            __builtin_nontemporal_store(sv, (f32x4*)(Ob + (size_t)j * Dv + 4 * l15));
        }
    }
}

extern "C" void kernel_launch(void* const* d_in, const int* in_sizes, int n_in,
                              void* d_out, int out_size, void* d_ws, size_t ws_size,
                              hipStream_t stream) {
    const float* X    = (const float*)d_in[0];
    const float* A    = (const float*)d_in[1];
    const int*   mask = (const int*)d_in[2];
    const float* W1   = (const float*)d_in[3];
    const float* b1   = (const float*)d_in[4];
    const float* W2   = (const float*)d_in[5];
    const float* b2   = (const float*)d_in[6];
    float* out = (float*)d_out;

    dim3 grid(Nv, Bv);   // (i, b): blocks sharing b are adjacent -> A[b] L2-hot

    if (ws_size >= (size_t)WS_NEED) {
        unsigned char* ws = (unsigned char*)d_ws;
        unsigned short* wpk  = (unsigned short*)ws;
        int*            flag = (int*)(ws + FLAG_OFF_B);
        unsigned short* apk  = (unsigned short*)(ws + APK_OFF_B);
        pack_all<<<517, 256, 0, stream>>>(A, W1, W2, b1, b2, wpk, apk, flag);
        nested_conv_mfma<true><<<grid, 256, 0, stream>>>(
            X, A, mask, W1, b1, W2, b2, wpk, apk, flag, out);
    } else {
        nested_conv_mfma<false><<<grid, 256, 0, stream>>>(
            X, A, mask, W1, b1, W2, b2, nullptr, nullptr, nullptr, out);
    }
}